// Round 6
// baseline (268.623 us; speedup 1.0000x reference)
//
#include <hip/hip_runtime.h>
#include <math.h>

#define NHID 128

typedef __bf16 bf16x8 __attribute__((ext_vector_type(8)));
typedef float f32x4 __attribute__((ext_vector_type(4)));

__device__ __forceinline__ unsigned int pack_bf16_rn(float f0, float f1) {
  unsigned int u0 = __float_as_uint(f0) + 0x8000u;
  unsigned int u1 = __float_as_uint(f1) + 0x8000u;
  return __builtin_amdgcn_perm(u1, u0, 0x07060302u);   // mem order: lo=f0, hi=f1
}
__device__ __forceinline__ unsigned short f2bf(float f) {
  return (unsigned short)((__float_as_uint(f) + 0x8000u) >> 16);
}
union frag_u { unsigned int u[4]; bf16x8 v; };

// ============================================================================
// Phase 1: per-node C rows (512 B): u = x@W1a + b1 (bf16), v = x@W1b (bf16),
// stored in MFMA-D-natural permuted order (validated r5):
//   u[chunk c of lane m15] = hidden col n = c*16 + m15.
// M=16 rows/wave (acc[16]=64 regs — the proven no-spill tile, r4) +
// dense 16B-store epilogue (r5). Per strip: 8 loads, 64 MFMA, 8 stores.
// ============================================================================
__global__ __launch_bounds__(256, 2)   // 256-reg cap; budget ~120 -> no spill
void precompute_uv(const float* __restrict__ inputs,
                   const float* __restrict__ W1,
                   const float* __restrict__ bias1,
                   unsigned short* __restrict__ C,
                   int n_nodes)
{
  // Combined B (K=128, N=256): Bc[k][n] = n<128 ? W1[k][n] : W1[128+k][n-128]
  // in MFMA B-frag-major order (verified r1-r5): 64 KB -> 2 blocks/CU.
  __shared__ __align__(16) unsigned short sB[4 * 16 * 64 * 8];

  const int tid = threadIdx.x;
  for (int i = tid; i < 256 * NHID / 4; i += 256) {
    float4 w = ((const float4*)W1)[i];
    int base = i * 4;
    int r  = base >> 7;          // W1 row (0..255)
    int n0 = base & 127;
    int k  = (r < 128) ? r : (r - 128);
    int nb = (r < 128) ? n0 : (n0 + 128);
    int ks = k >> 5, qq = (k >> 3) & 3, j = k & 7;
    #pragma unroll
    for (int c = 0; c < 4; ++c) {
      int n = nb + c;
      sB[(((ks * 16 + (n >> 4)) * 64) + (qq * 16 + (n & 15))) * 8 + j] = f2bf((&w.x)[c]);
    }
  }
  __syncthreads();   // only barrier

  const int lane = tid & 63;
  const int wv   = tid >> 6;
  const int m15  = lane & 15;
  const int q    = lane >> 4;

  float b1v[8];
  #pragma unroll
  for (int nt = 0; nt < 8; ++nt) b1v[nt] = bias1[nt * 16 + m15];

  const bf16x8* __restrict__ bfrags = (const bf16x8*)sB;
  const int gwave   = blockIdx.x * 4 + wv;
  const int nwaves  = gridDim.x * 4;
  const int nstrips = (n_nodes + 15) >> 4;   // 16-row strips

  for (int strip = gwave; strip < nstrips; strip += nwaves) {
    int row = strip * 16 + m15;
    if (row >= n_nodes) row = n_nodes - 1;
    const float* ap = inputs + (size_t)row * NHID;

    // all 8 A loads in flight up front (A-frag: row=m15, k=ks*32+q*8+j)
    float4 r0[4], r1[4];
    #pragma unroll
    for (int d = 0; d < 4; ++d) {
      r0[d] = *(const float4*)(ap + d * 32 + q * 8);
      r1[d] = *(const float4*)(ap + d * 32 + q * 8 + 4);
    }

    f32x4 acc[16];
    #pragma unroll
    for (int nt = 0; nt < 16; ++nt) acc[nt] = (f32x4){0.f, 0.f, 0.f, 0.f};

    #pragma unroll
    for (int ks = 0; ks < 4; ++ks) {
      frag_u cv;
      cv.u[0] = pack_bf16_rn(r0[ks].x, r0[ks].y);
      cv.u[1] = pack_bf16_rn(r0[ks].z, r0[ks].w);
      cv.u[2] = pack_bf16_rn(r1[ks].x, r1[ks].y);
      cv.u[3] = pack_bf16_rn(r1[ks].z, r1[ks].w);
      bf16x8 af = cv.v;
      const bf16x8* bp = bfrags + (ks * 16) * 64 + lane;
      #pragma unroll
      for (int nt = 0; nt < 16; ++nt)
        acc[nt] = __builtin_amdgcn_mfma_f32_16x16x32_bf16(af, bp[nt * 64], acc[nt], 0, 0, 0);
    }

    // Dense epilogue (validated r5): D col = lane&15, row = q*4+r.
    // Each lane packs its 8 u vals (+b1) and 8 v vals into one 16B chunk each;
    // per store instr the wave covers 4 rows x 256 B dense.
    #pragma unroll
    for (int r = 0; r < 4; ++r) {
      int m = strip * 16 + q * 4 + r;
      if (m < n_nodes) {
        uint4 up, vp;
        up.x = pack_bf16_rn(acc[0][r] + b1v[0], acc[1][r] + b1v[1]);
        up.y = pack_bf16_rn(acc[2][r] + b1v[2], acc[3][r] + b1v[3]);
        up.z = pack_bf16_rn(acc[4][r] + b1v[4], acc[5][r] + b1v[5]);
        up.w = pack_bf16_rn(acc[6][r] + b1v[6], acc[7][r] + b1v[7]);
        vp.x = pack_bf16_rn(acc[8][r],  acc[9][r]);
        vp.y = pack_bf16_rn(acc[10][r], acc[11][r]);
        vp.z = pack_bf16_rn(acc[12][r], acc[13][r]);
        vp.w = pack_bf16_rn(acc[14][r], acc[15][r]);
        unsigned short* crow = C + (size_t)m * 256;
        *(uint4*)(crow + m15 * 8)       = up;   // u-half
        *(uint4*)(crow + 128 + m15 * 8) = vp;   // v-half
      }
    }
  }
}

// ============================================================================
// Phase 2: out[e] = sigmoid( sum relu(u[x[e]] + v[y[e]]) . W2perm + b2 )
// 16 lanes/edge, 4 edges/wave/iter, DEPTH-4 row-gather ring (8 outstanding
// 16B loads/lane) + idx pipelined 2 slots ahead. Latency-bound fix for r4/r5.
// ============================================================================
__global__ __launch_bounds__(256, 4)
void edge_decode(const unsigned short* __restrict__ C,
                 const int* __restrict__ x_idx,
                 const int* __restrict__ y_idx,
                 const float* __restrict__ W2,
                 const float* __restrict__ bias2,
                 float* __restrict__ out,
                 int n_edges)
{
  const int tid  = threadIdx.x;
  const int lane = tid & 63;
  const int wv   = tid >> 6;
  const int sub  = lane & 15;   // 16-B slice within the 256-B half-row
  const int eo   = lane >> 4;   // edge within the wave's 4-edge batch

  float w2v[8];
  #pragma unroll
  for (int c = 0; c < 8; ++c) w2v[c] = W2[c * 16 + sub];
  const float b2 = bias2[0];

  const int gwave = blockIdx.x * 4 + wv;
  const int SE    = gridDim.x * 4 * 4;
  const int e0    = gwave * 4;
  if (e0 >= n_edges) return;

  auto clampe = [n_edges](int x) { return (x < n_edges) ? x : (n_edges - 1); };

  // prologue: rows for iters 0..3 (all 8 loads independent), idx for iters 4,5
  uint4 Ru[4], Rv[4];
  #pragma unroll
  for (int s = 0; s < 4; ++s) {
    int es = clampe(e0 + s * SE + eo);
    int xi = x_idx[es], yi = y_idx[es];
    Ru[s] = *(const uint4*)(C + (size_t)xi * 256 + sub * 8);
    Rv[s] = *(const uint4*)(C + (size_t)yi * 256 + 128 + sub * 8);
  }
  int xq[2], yq[2];
  {
    int e4 = clampe(e0 + 4 * SE + eo);
    int e5 = clampe(e0 + 5 * SE + eo);
    xq[0] = x_idx[e4]; yq[0] = y_idx[e4];
    xq[1] = x_idx[e5]; yq[1] = y_idx[e5];
  }

  int it = 0;
  #pragma unroll 4
  for (int e = e0; e < n_edges; e += SE, ++it) {
    const int s = it & 3;

    float t = 0.f;
    #pragma unroll
    for (int p = 0; p < 4; ++p) {
      unsigned int a = (&Ru[s].x)[p], b = (&Rv[s].x)[p];
      float h0 = fmaxf(__uint_as_float(a << 16)         + __uint_as_float(b << 16),         0.f);
      float h1 = fmaxf(__uint_as_float(a & 0xffff0000u) + __uint_as_float(b & 0xffff0000u), 0.f);
      t = fmaf(h0, w2v[2 * p], t);
      t = fmaf(h1, w2v[2 * p + 1], t);
    }
    t += __shfl_xor(t, 1);
    t += __shfl_xor(t, 2);
    t += __shfl_xor(t, 4);
    t += __shfl_xor(t, 8);
    int epos = e + eo;
    if (sub == 0 && epos < n_edges)
      out[epos] = 1.f / (1.f + __expf(-(t + b2)));

    // refill slot s with rows for iter it+4; fetch idx for iter it+6
    int xi = xq[it & 1], yi = yq[it & 1];
    Ru[s] = *(const uint4*)(C + (size_t)xi * 256 + sub * 8);
    Rv[s] = *(const uint4*)(C + (size_t)yi * 256 + 128 + sub * 8);
    int e6 = clampe(e + 6 * SE + eo);
    xq[it & 1] = x_idx[e6]; yq[it & 1] = y_idx[e6];
  }
}

// ============================================================================
// Fallback (ws too small): round-3/4 fused kernel (proven correct).
// ============================================================================
__global__ __launch_bounds__(256, 2)
void mlp_edge_fused(const float* __restrict__ inputs,
                    const int* __restrict__ x_idx,
                    const int* __restrict__ y_idx,
                    const float* __restrict__ W1,
                    const float* __restrict__ bias1,
                    const float* __restrict__ W2,
                    const float* __restrict__ bias2,
                    float* __restrict__ out,
                    int n_edges)
{
  __shared__ __align__(16) unsigned short sB[8 * 8 * 64 * 8];
  const int tid = threadIdx.x;
  for (int i = tid; i < 256 * NHID / 4; i += 256) {
    float4 w = ((const float4*)W1)[i];
    int base = i * 4;
    int k  = base >> 7;
    int n0 = base & 127;
    int ks = k >> 5, qq = (k >> 3) & 3, j = k & 7;
    #pragma unroll
    for (int c = 0; c < 4; ++c) {
      int n = n0 + c;
      sB[(((ks * 8 + (n >> 4)) * 64) + (qq * 16 + (n & 15))) * 8 + j] = f2bf((&w.x)[c]);
    }
  }
  __syncthreads();

  const int lane = tid & 63;
  const int wv   = tid >> 6;
  const int m15  = lane & 15;
  const int q    = lane >> 4;

  float b1v[8], w2v[8];
  #pragma unroll
  for (int nt = 0; nt < 8; ++nt) {
    b1v[nt] = bias1[nt * 16 + m15];
    w2v[nt] = W2[nt * 16 + m15];
  }
  const float b2 = bias2[0];

  const int gwave   = blockIdx.x * 4 + wv;
  const int nwaves  = gridDim.x * 4;
  const int nstrips = (n_edges + 15) >> 4;
  const bf16x8* __restrict__ bfrags = (const bf16x8*)sB;

  int ix_n = 0, iy_n = 0;
  if (gwave < nstrips) {
    int e = gwave * 16 + m15; if (e >= n_edges) e = n_edges - 1;
    ix_n = x_idx[e]; iy_n = y_idx[e];
  }

  for (int strip = gwave; strip < nstrips; strip += nwaves) {
    const float* ax = inputs + (size_t)ix_n * NHID;
    const float* ay = inputs + (size_t)iy_n * NHID;
    int nxt = strip + nwaves;
    if (nxt < nstrips) {
      int e = nxt * 16 + m15; if (e >= n_edges) e = n_edges - 1;
      ix_n = x_idx[e]; iy_n = y_idx[e];
    }
    float4 ring0[4], ring1[4];
    #pragma unroll
    for (int d = 0; d < 4; ++d) {
      ring0[d] = *(const float4*)(ax + d * 32 + q * 8);
      ring1[d] = *(const float4*)(ax + d * 32 + q * 8 + 4);
    }
    f32x4 acc[8];
    #pragma unroll
    for (int nt = 0; nt < 8; ++nt) acc[nt] = (f32x4){0.f, 0.f, 0.f, 0.f};
    #pragma unroll
    for (int ks = 0; ks < 8; ++ks) {
      float4 a0 = ring0[ks & 3], a1 = ring1[ks & 3];
      frag_u cv;
      cv.u[0] = pack_bf16_rn(a0.x, a0.y);
      cv.u[1] = pack_bf16_rn(a0.z, a0.w);
      cv.u[2] = pack_bf16_rn(a1.x, a1.y);
      cv.u[3] = pack_bf16_rn(a1.z, a1.w);
      bf16x8 af = cv.v;
      if (ks < 4) {
        ring0[ks & 3] = *(const float4*)(ay + ks * 32 + q * 8);
        ring1[ks & 3] = *(const float4*)(ay + ks * 32 + q * 8 + 4);
      }
      const bf16x8* bp = bfrags + (ks * 8) * 64 + lane;
      #pragma unroll
      for (int nt = 0; nt < 8; ++nt)
        acc[nt] = __builtin_amdgcn_mfma_f32_16x16x32_bf16(af, bp[nt * 64], acc[nt], 0, 0, 0);
    }
    float4 sv;
    #pragma unroll
    for (int r = 0; r < 4; ++r) {
      float t = 0.f;
      #pragma unroll
      for (int nt = 0; nt < 8; ++nt) {
        float h = acc[nt][r] + b1v[nt];
        h = fmaxf(h, 0.f);
        t = fmaf(h, w2v[nt], t);
      }
      t += __shfl_xor(t, 1);
      t += __shfl_xor(t, 2);
      t += __shfl_xor(t, 4);
      t += __shfl_xor(t, 8);
      (&sv.x)[r] = t;
    }
    if (m15 == 0) {
      int e = strip * 16 + q * 4;
      float4 ov;
      #pragma unroll
      for (int r = 0; r < 4; ++r)
        (&ov.x)[r] = 1.f / (1.f + __expf(-((&sv.x)[r] + b2)));
      if (e + 3 < n_edges) *(float4*)(out + e) = ov;
      else {
        #pragma unroll
        for (int r = 0; r < 4; ++r)
          if (e + r < n_edges) out[e + r] = (&ov.x)[r];
      }
    }
  }
}

extern "C" void kernel_launch(void* const* d_in, const int* in_sizes, int n_in,
                              void* d_out, int out_size, void* d_ws, size_t ws_size,
                              hipStream_t stream) {
  const float* inputs = (const float*)d_in[0];
  const int*   x_idx  = (const int*)d_in[1];
  const int*   y_idx  = (const int*)d_in[2];
  const float* W1     = (const float*)d_in[3];
  const float* bias1  = (const float*)d_in[4];
  const float* W2     = (const float*)d_in[5];
  const float* bias2  = (const float*)d_in[6];
  float* out = (float*)d_out;
  const int n_edges = in_sizes[1];
  const int n_nodes = in_sizes[0] / NHID;

  const size_t need = (size_t)n_nodes * 256 * sizeof(unsigned short);
  if (ws_size >= need) {
    unsigned short* C = (unsigned short*)d_ws;
    hipLaunchKernelGGL(precompute_uv, dim3(512), dim3(256), 0, stream,
                       inputs, W1, bias1, C, n_nodes);
    hipLaunchKernelGGL(edge_decode, dim3(4096), dim3(256), 0, stream,
                       C, x_idx, y_idx, W2, bias2, out, n_edges);
  } else {
    hipLaunchKernelGGL(mlp_edge_fused, dim3(512), dim3(256), 0, stream,
                       inputs, x_idx, y_idx, W1, bias1, W2, bias2, out, n_edges);
  }
}